// Round 5
// baseline (137.442 us; speedup 1.0000x reference)
//
#include <hip/hip_runtime.h>

// CenterLoss: loss = 0.5/B * (FF - 2*DOT + CC)
//   FF  = sum_i ||f_i||^2
//   DOT = sum_c sum_vec_c . newc_c
//   CC  = sum_c count_c * ||newc_c||^2
//   newc_c = count_c>0 ? 0.5*centers_c + 0.5*sum_vec_c/count_c : centers_c
// One pass over feats (134 MB): counting-sort binning, then SEGS blocks per
// class gather rows and atomicAdd partial sums into sums[C][D] (1 MB in L2).

#define DDIM 256
#define DDIM4 64
#define SEGS 4
#define CHUNK 1024

// Zero counts[1024] + scalars[16] + sums[C*DDIM] = 257040 ints = 64260 int4.
__global__ __launch_bounds__(256) void k0_zero(int4* __restrict__ p, int n4) {
    int stride = gridDim.x * 256;
    int4 z = make_int4(0, 0, 0, 0);
    for (int i = blockIdx.x * 256 + threadIdx.x; i < n4; i += stride) p[i] = z;
}

__global__ __launch_bounds__(256) void k1_hist(const int* __restrict__ labels,
                                               int* __restrict__ counts,
                                               int B, int C) {
    __shared__ int h[1024];
    for (int i = threadIdx.x; i < 1024; i += 256) h[i] = 0;
    __syncthreads();
    int stride = gridDim.x * 256;
    for (int i = blockIdx.x * 256 + threadIdx.x; i < B; i += stride)
        atomicAdd(&h[labels[i]], 1);
    __syncthreads();
    for (int i = threadIdx.x; i < C; i += 256) {
        int v = h[i];
        if (v) atomicAdd(&counts[i], v);
    }
}

// Single-block Hillis-Steele scan over <=1024 bins -> exclusive offsets + cursor.
__global__ __launch_bounds__(1024) void k2_scan(const int* __restrict__ counts,
                                                int* __restrict__ offsets,
                                                int* __restrict__ cursor, int C) {
    __shared__ int sc[1024];
    int t = threadIdx.x;
    int mine = (t < C) ? counts[t] : 0;
    sc[t] = mine;
    __syncthreads();
    for (int off = 1; off < 1024; off <<= 1) {
        int add = (t >= off) ? sc[t - off] : 0;
        __syncthreads();
        sc[t] += add;
        __syncthreads();
    }
    if (t < C) {
        int e = sc[t] - mine;
        offsets[t] = e;
        cursor[t]  = e;
    }
}

__global__ __launch_bounds__(256) void k3_scatter(const int* __restrict__ labels,
                                                  int* __restrict__ cursor,
                                                  int* __restrict__ rowidx, int B) {
    int stride = gridDim.x * 256;
    for (int i = blockIdx.x * 256 + threadIdx.x; i < B; i += stride) {
        int c = labels[i];
        int pos = atomicAdd(&cursor[c], 1);
        rowidx[pos] = i;
    }
}

// SEGS blocks per class; block = (class, segment). 4 waves/block; wave w sums
// rows w, w+4, ...; lane l holds float4 slot l (dims 4l..4l+3). Partial sums
// combined in LDS then atomicAdd'ed into sums[c][*]; FF into scalars[0].
__global__ __launch_bounds__(256) void k4_gather(const float4* __restrict__ feats4,
                                                 const int* __restrict__ rowidx,
                                                 const int* __restrict__ counts,
                                                 const int* __restrict__ offsets,
                                                 float* __restrict__ sums,
                                                 float* __restrict__ scalars) {
    __shared__ int rows[CHUNK];
    __shared__ float comb[4 * DDIM];
    __shared__ float redf[4];

    int c = blockIdx.x >> 2;          // SEGS == 4
    int s = blockIdx.x & 3;
    int count = counts[c];
    int seg = (count + SEGS - 1) >> 2;
    int s0 = s * seg;
    int n = min(seg, count - s0);
    if (n <= 0) return;               // uniform across the block (no barrier yet)
    int start = offsets[c] + s0;

    int t = threadIdx.x;
    int wave = t >> 6, lane = t & 63;

    float4 acc = make_float4(0.f, 0.f, 0.f, 0.f);
    float ff = 0.f;

    for (int cs = 0; cs < n; cs += CHUNK) {
        int m = min(CHUNK, n - cs);
        for (int i = t; i < m; i += 256) rows[i] = rowidx[start + cs + i];
        __syncthreads();
        int r = wave;
        for (; r + 12 < m; r += 16) {
            int r0 = rows[r], r1 = rows[r + 4], r2 = rows[r + 8], r3 = rows[r + 12];
            float4 v0 = feats4[r0 * DDIM4 + lane];
            float4 v1 = feats4[r1 * DDIM4 + lane];
            float4 v2 = feats4[r2 * DDIM4 + lane];
            float4 v3 = feats4[r3 * DDIM4 + lane];
            acc.x += v0.x; acc.y += v0.y; acc.z += v0.z; acc.w += v0.w;
            ff += v0.x*v0.x + v0.y*v0.y + v0.z*v0.z + v0.w*v0.w;
            acc.x += v1.x; acc.y += v1.y; acc.z += v1.z; acc.w += v1.w;
            ff += v1.x*v1.x + v1.y*v1.y + v1.z*v1.z + v1.w*v1.w;
            acc.x += v2.x; acc.y += v2.y; acc.z += v2.z; acc.w += v2.w;
            ff += v2.x*v2.x + v2.y*v2.y + v2.z*v2.z + v2.w*v2.w;
            acc.x += v3.x; acc.y += v3.y; acc.z += v3.z; acc.w += v3.w;
            ff += v3.x*v3.x + v3.y*v3.y + v3.z*v3.z + v3.w*v3.w;
        }
        for (; r < m; r += 4) {
            float4 v = feats4[rows[r] * DDIM4 + lane];
            acc.x += v.x; acc.y += v.y; acc.z += v.z; acc.w += v.w;
            ff += v.x*v.x + v.y*v.y + v.z*v.z + v.w*v.w;
        }
        __syncthreads();
    }

    comb[wave * DDIM + lane * 4 + 0] = acc.x;
    comb[wave * DDIM + lane * 4 + 1] = acc.y;
    comb[wave * DDIM + lane * 4 + 2] = acc.z;
    comb[wave * DDIM + lane * 4 + 3] = acc.w;
    __syncthreads();

    float v = comb[t] + comb[DDIM + t] + comb[2 * DDIM + t] + comb[3 * DDIM + t];
    atomicAdd(&sums[c * DDIM + t], v);

#pragma unroll
    for (int off = 32; off > 0; off >>= 1) ff += __shfl_down(ff, off);
    if (lane == 0) redf[wave] = ff;
    __syncthreads();
    if (t == 0) atomicAdd(&scalars[0], redf[0] + redf[1] + redf[2] + redf[3]);
}

// One block per class: compute DOT and CC contributions from sums/counts/centers.
__global__ __launch_bounds__(256) void k5_epilogue(const float* __restrict__ sums,
                                                   const float* __restrict__ centers,
                                                   const int* __restrict__ counts,
                                                   float* __restrict__ scalars) {
    __shared__ float red[8];
    int c = blockIdx.x;
    int t = threadIdx.x;
    int wave = t >> 6, lane = t & 63;
    int count = counts[c];

    float s  = sums[c * DDIM + t];
    float co = centers[c * DDIM + t];
    float nc = (count > 0) ? 0.5f * co + 0.5f * s / (float)count : co;
    float dotv = nc * s;                    // count==0 -> s==0 -> 0
    float ccv  = nc * nc * (float)count;    // count==0 -> 0

#pragma unroll
    for (int off = 32; off > 0; off >>= 1) {
        dotv += __shfl_down(dotv, off);
        ccv  += __shfl_down(ccv, off);
    }
    if (lane == 0) { red[wave * 2 + 0] = dotv; red[wave * 2 + 1] = ccv; }
    __syncthreads();
    if (t == 0) {
        atomicAdd(&scalars[1], red[0] + red[2] + red[4] + red[6]);
        atomicAdd(&scalars[2], red[1] + red[3] + red[5] + red[7]);
    }
}

__global__ void k6_final(const float* __restrict__ scalars, float* __restrict__ out, int B) {
    if (threadIdx.x == 0 && blockIdx.x == 0) {
        out[0] = 0.5f / (float)B * (scalars[0] - 2.f * scalars[1] + scalars[2]);
    }
}

extern "C" void kernel_launch(void* const* d_in, const int* in_sizes, int n_in,
                              void* d_out, int out_size, void* d_ws, size_t ws_size,
                              hipStream_t stream) {
    const float* feats   = (const float*)d_in[0];
    const float* centers = (const float*)d_in[1];
    const int*   labels  = (const int*)d_in[2];

    int B = in_sizes[2];              // 131072
    int Dv = in_sizes[0] / B;         // 256 (kernel assumes 256)
    int C = in_sizes[1] / Dv;         // 1000
    (void)Dv; (void)n_in; (void)ws_size;

    // Workspace layout (ints): [counts 1024][scalars 16][sums C*DDIM][offsets 1024][cursor 1024][rowidx B]
    int* W = (int*)d_ws;
    int* counts    = W;                        // 1024
    float* scalars = (float*)(W + 1024);       // 16 (FF, DOT, CC used)
    float* sums    = (float*)(W + 1040);       // C*DDIM = 256000
    int* offsets   = W + 1040 + C * DDIM;      // 1024
    int* cursor    = offsets + 1024;           // 1024
    int* rowidx    = cursor + 1024;            // B

    int zero_ints = 1040 + C * DDIM;           // counts + scalars + sums
    k0_zero<<<256, 256, 0, stream>>>((int4*)W, zero_ints / 4);
    k1_hist<<<256, 256, 0, stream>>>(labels, counts, B, C);
    k2_scan<<<1, 1024, 0, stream>>>(counts, offsets, cursor, C);
    int sblocks = (B + 255) / 256;
    if (sblocks > 512) sblocks = 512;
    k3_scatter<<<sblocks, 256, 0, stream>>>(labels, cursor, rowidx, B);
    k4_gather<<<C * SEGS, 256, 0, stream>>>((const float4*)feats, rowidx,
                                            counts, offsets, sums, scalars);
    k5_epilogue<<<C, 256, 0, stream>>>(sums, centers, counts, scalars);
    k6_final<<<1, 64, 0, stream>>>(scalars, (float*)d_out, B);
}

// Round 6
// 116.768 us; speedup vs baseline: 1.1771x; 1.1771x over previous
//
#include <hip/hip_runtime.h>

// CenterLoss: loss = 0.5/B * (FF - 2*DOT + CC)
//   FF  = sum_i ||f_i||^2
//   DOT = sum_c sum_vec_c . newc_c
//   CC  = sum_c count_c * ||newc_c||^2
//   newc_c = count_c>0 ? 0.5*centers_c + 0.5*sum_vec_c/count_c : centers_c
// One pass over feats (134 MB): counting-sort binning, one block per class,
// 8-deep per-wave load pipeline, inline DOT/CC epilogue, last-block finalize.

#define DDIM 256
#define DDIM4 64

// ws (ints): counts[1024] | offsets[1024] | cursor[1024] | scalars[16] | rowidx[B]
// scalars: [0]=FF [1]=DOT [2]=CC, ticket at int slot 3084 (scalars[12..])

__global__ __launch_bounds__(1024) void k0_zero(int* __restrict__ counts,
                                                int* __restrict__ scal16) {
    int t = threadIdx.x;
    counts[t] = 0;
    if (t < 16) scal16[t] = 0;
}

__global__ __launch_bounds__(256) void k1_hist(const int* __restrict__ labels,
                                               int* __restrict__ counts,
                                               int B, int C) {
    __shared__ int h[1024];
    for (int i = threadIdx.x; i < 1024; i += 256) h[i] = 0;
    __syncthreads();
    int stride = gridDim.x * 256;
    for (int i = blockIdx.x * 256 + threadIdx.x; i < B; i += stride)
        atomicAdd(&h[labels[i]], 1);
    __syncthreads();
    for (int i = threadIdx.x; i < C; i += 256) {
        int v = h[i];
        if (v) atomicAdd(&counts[i], v);
    }
}

// Single-block Hillis-Steele scan over <=1024 bins -> exclusive offsets + cursor.
__global__ __launch_bounds__(1024) void k2_scan(const int* __restrict__ counts,
                                                int* __restrict__ offsets,
                                                int* __restrict__ cursor, int C) {
    __shared__ int sc[1024];
    int t = threadIdx.x;
    int mine = (t < C) ? counts[t] : 0;
    sc[t] = mine;
    __syncthreads();
    for (int off = 1; off < 1024; off <<= 1) {
        int add = (t >= off) ? sc[t - off] : 0;
        __syncthreads();
        sc[t] += add;
        __syncthreads();
    }
    if (t < C) {
        int e = sc[t] - mine;
        offsets[t] = e;
        cursor[t]  = e;
    }
}

__global__ __launch_bounds__(256) void k3_scatter(const int* __restrict__ labels,
                                                  int* __restrict__ cursor,
                                                  int* __restrict__ rowidx, int B) {
    int stride = gridDim.x * 256;
    for (int i = blockIdx.x * 256 + threadIdx.x; i < B; i += stride) {
        int c = labels[i];
        int pos = atomicAdd(&cursor[c], 1);
        rowidx[pos] = i;
    }
}

// One block per class; 4 waves; wave w sums a CONTIGUOUS run of rows with an
// 8-deep load pipeline (8 independent float4 loads in flight per lane). Lane l
// owns dims 4l..4l+3. Block combines wave partials in LDS, computes DOT/CC
// against its centers row inline, atomics into scalars; last block finalizes.
__global__ __launch_bounds__(256) void k4_class(const float4* __restrict__ feats4,
                                                const float* __restrict__ centers,
                                                const int* __restrict__ rowidx,
                                                const int* __restrict__ counts,
                                                const int* __restrict__ offsets,
                                                float* __restrict__ scalars,
                                                int* __restrict__ ticket,
                                                float* __restrict__ out,
                                                int nblocks, float invB) {
    __shared__ float comb[4 * DDIM];
    __shared__ float red[12];
    __shared__ int lastflag;

    int c = blockIdx.x;
    int count = counts[c];
    int start = offsets[c];
    int t = threadIdx.x, wave = t >> 6, lane = t & 63;

    int per = (count + 3) >> 2;
    int wbeg = wave * per;
    int wend = min(count, wbeg + per);

    float4 acc = make_float4(0.f, 0.f, 0.f, 0.f);
    float ff = 0.f;

    int i = wbeg;
    for (; i + 8 <= wend; i += 8) {
        int j[8];
        float4 v[8];
#pragma unroll
        for (int k = 0; k < 8; ++k) j[k] = rowidx[start + i + k];
#pragma unroll
        for (int k = 0; k < 8; ++k) v[k] = feats4[j[k] * DDIM4 + lane];
#pragma unroll
        for (int k = 0; k < 8; ++k) {
            acc.x += v[k].x; acc.y += v[k].y; acc.z += v[k].z; acc.w += v[k].w;
            ff += v[k].x*v[k].x + v[k].y*v[k].y + v[k].z*v[k].z + v[k].w*v[k].w;
        }
    }
    for (; i < wend; ++i) {
        float4 v = feats4[rowidx[start + i] * DDIM4 + lane];
        acc.x += v.x; acc.y += v.y; acc.z += v.z; acc.w += v.w;
        ff += v.x*v.x + v.y*v.y + v.z*v.z + v.w*v.w;
    }

    comb[wave * DDIM + lane * 4 + 0] = acc.x;
    comb[wave * DDIM + lane * 4 + 1] = acc.y;
    comb[wave * DDIM + lane * 4 + 2] = acc.z;
    comb[wave * DDIM + lane * 4 + 3] = acc.w;
    __syncthreads();

    // thread t owns dimension t
    float s  = comb[t] + comb[DDIM + t] + comb[2 * DDIM + t] + comb[3 * DDIM + t];
    float co = centers[c * DDIM + t];
    float nc = (count > 0) ? 0.5f * co + 0.5f * s / (float)count : co;
    float dotv = nc * s;                    // count==0 -> s==0 -> 0
    float ccv  = nc * nc * (float)count;    // count==0 -> 0

#pragma unroll
    for (int off = 32; off > 0; off >>= 1) {
        ff   += __shfl_down(ff, off);
        dotv += __shfl_down(dotv, off);
        ccv  += __shfl_down(ccv, off);
    }
    if (lane == 0) {
        red[wave * 3 + 0] = ff;
        red[wave * 3 + 1] = dotv;
        red[wave * 3 + 2] = ccv;
    }
    __syncthreads();
    if (t == 0) {
        atomicAdd(&scalars[0], red[0] + red[3] + red[6] + red[9]);
        atomicAdd(&scalars[1], red[1] + red[4] + red[7] + red[10]);
        atomicAdd(&scalars[2], red[2] + red[5] + red[8] + red[11]);
        __threadfence();
        int old = atomicAdd(ticket, 1);
        lastflag = (old == nblocks - 1) ? 1 : 0;
    }
    __syncthreads();
    if (lastflag && t == 0) {
        __threadfence();
        // atomic reads: device-scope coherent across XCDs
        float a = atomicAdd(&scalars[0], 0.f);
        float b = atomicAdd(&scalars[1], 0.f);
        float e = atomicAdd(&scalars[2], 0.f);
        out[0] = 0.5f * invB * (a - 2.f * b + e);
    }
}

extern "C" void kernel_launch(void* const* d_in, const int* in_sizes, int n_in,
                              void* d_out, int out_size, void* d_ws, size_t ws_size,
                              hipStream_t stream) {
    const float* feats   = (const float*)d_in[0];
    const float* centers = (const float*)d_in[1];
    const int*   labels  = (const int*)d_in[2];

    int B = in_sizes[2];              // 131072
    int Dv = in_sizes[0] / B;         // 256 (kernel assumes 256)
    int C = in_sizes[1] / Dv;         // 1000
    (void)Dv; (void)n_in; (void)ws_size; (void)out_size;

    int* W = (int*)d_ws;
    int* counts    = W;                        // 1024
    int* offsets   = W + 1024;                 // 1024
    int* cursor    = W + 2048;                 // 1024
    float* scalars = (float*)(W + 3072);       // 16: [0]FF [1]DOT [2]CC
    int* ticket    = W + 3072 + 12;            // scalars[12] slot
    int* rowidx    = W + 3072 + 16;            // B

    k0_zero<<<1, 1024, 0, stream>>>(counts, W + 3072);
    k1_hist<<<256, 256, 0, stream>>>(labels, counts, B, C);
    k2_scan<<<1, 1024, 0, stream>>>(counts, offsets, cursor, C);
    int sblocks = (B + 255) / 256;
    if (sblocks > 512) sblocks = 512;
    k3_scatter<<<sblocks, 256, 0, stream>>>(labels, cursor, rowidx, B);
    k4_class<<<C, 256, 0, stream>>>((const float4*)feats, centers, rowidx,
                                    counts, offsets, scalars, ticket,
                                    (float*)d_out, C, 1.0f / (float)B);
}

// Round 7
// 114.763 us; speedup vs baseline: 1.1976x; 1.0175x over previous
//
#include <hip/hip_runtime.h>

// CenterLoss: loss = 0.5/B * (FF - 2*DOT + CC)
//   FF  = sum_i ||f_i||^2
//   DOT = sum_c sum_vec_c . newc_c
//   CC  = sum_c count_c * ||newc_c||^2
//   newc_c = count_c>0 ? 0.5*centers_c + 0.5*sum_vec_c/count_c : centers_c
// One pass over feats (134 MB): counting-sort binning, one block (512 thr,
// 8 waves) per class, LDS-staged indices, stride-by-wave 4x-unrolled gather
// (R4's proven ~4-deep load pipeline) at 32 waves/CU for latency hiding.

#define DDIM 256
#define DDIM4 64
#define CHUNK 1024

// ws (ints): counts[1024] | offsets[1024] | cursor[1024] | scalars[16] | rowidx[B]
// scalars: [0]=FF [1]=DOT [2]=CC, ticket at scalars slot 12

__global__ __launch_bounds__(1024) void k0_zero(int* __restrict__ counts,
                                                int* __restrict__ scal16) {
    int t = threadIdx.x;
    counts[t] = 0;
    if (t < 16) scal16[t] = 0;
}

__global__ __launch_bounds__(256) void k1_hist(const int* __restrict__ labels,
                                               int* __restrict__ counts,
                                               int B, int C) {
    __shared__ int h[1024];
    for (int i = threadIdx.x; i < 1024; i += 256) h[i] = 0;
    __syncthreads();
    int stride = gridDim.x * 256;
    for (int i = blockIdx.x * 256 + threadIdx.x; i < B; i += stride)
        atomicAdd(&h[labels[i]], 1);
    __syncthreads();
    for (int i = threadIdx.x; i < C; i += 256) {
        int v = h[i];
        if (v) atomicAdd(&counts[i], v);
    }
}

// Single-block Hillis-Steele scan over <=1024 bins -> exclusive offsets + cursor.
__global__ __launch_bounds__(1024) void k2_scan(const int* __restrict__ counts,
                                                int* __restrict__ offsets,
                                                int* __restrict__ cursor, int C) {
    __shared__ int sc[1024];
    int t = threadIdx.x;
    int mine = (t < C) ? counts[t] : 0;
    sc[t] = mine;
    __syncthreads();
    for (int off = 1; off < 1024; off <<= 1) {
        int add = (t >= off) ? sc[t - off] : 0;
        __syncthreads();
        sc[t] += add;
        __syncthreads();
    }
    if (t < C) {
        int e = sc[t] - mine;
        offsets[t] = e;
        cursor[t]  = e;
    }
}

__global__ __launch_bounds__(256) void k3_scatter(const int* __restrict__ labels,
                                                  int* __restrict__ cursor,
                                                  int* __restrict__ rowidx, int B) {
    int stride = gridDim.x * 256;
    for (int i = blockIdx.x * 256 + threadIdx.x; i < B; i += stride) {
        int c = labels[i];
        int pos = atomicAdd(&cursor[c], 1);
        rowidx[pos] = i;
    }
}

// One block (8 waves) per class. Indices staged in LDS; wave w handles rows
// w, w+8, w+16, ... with a 4x unroll (4 independent named float4 loads in
// flight). Lane l owns dims 4l..4l+3. Wave partials combined in LDS; DOT/CC
// computed inline vs centers row; 3 scalar atomics; last block finalizes loss.
__global__ __launch_bounds__(512, 8) void k4_class(const float4* __restrict__ feats4,
                                                   const float* __restrict__ centers,
                                                   const int* __restrict__ rowidx,
                                                   const int* __restrict__ counts,
                                                   const int* __restrict__ offsets,
                                                   float* __restrict__ scalars,
                                                   int* __restrict__ ticket,
                                                   float* __restrict__ out,
                                                   int nblocks, float invB) {
    __shared__ int rows[CHUNK];
    __shared__ float comb[8 * DDIM];
    __shared__ float red[24];

    int c = blockIdx.x;
    int count = counts[c];
    int start = offsets[c];
    int t = threadIdx.x, wave = t >> 6, lane = t & 63;

    float4 acc = make_float4(0.f, 0.f, 0.f, 0.f);
    float ff = 0.f;

    for (int cs = 0; cs < count; cs += CHUNK) {
        int m = min(CHUNK, count - cs);
        for (int i = t; i < m; i += 512) rows[i] = rowidx[start + cs + i];
        __syncthreads();
        int r = wave;
        // 4 independent named loads per iteration, rows strided by 8 waves
        for (; r + 24 < m; r += 32) {
            int r0 = rows[r], r1 = rows[r + 8], r2 = rows[r + 16], r3 = rows[r + 24];
            float4 v0 = feats4[r0 * DDIM4 + lane];
            float4 v1 = feats4[r1 * DDIM4 + lane];
            float4 v2 = feats4[r2 * DDIM4 + lane];
            float4 v3 = feats4[r3 * DDIM4 + lane];
            acc.x += v0.x; acc.y += v0.y; acc.z += v0.z; acc.w += v0.w;
            ff += v0.x*v0.x + v0.y*v0.y + v0.z*v0.z + v0.w*v0.w;
            acc.x += v1.x; acc.y += v1.y; acc.z += v1.z; acc.w += v1.w;
            ff += v1.x*v1.x + v1.y*v1.y + v1.z*v1.z + v1.w*v1.w;
            acc.x += v2.x; acc.y += v2.y; acc.z += v2.z; acc.w += v2.w;
            ff += v2.x*v2.x + v2.y*v2.y + v2.z*v2.z + v2.w*v2.w;
            acc.x += v3.x; acc.y += v3.y; acc.z += v3.z; acc.w += v3.w;
            ff += v3.x*v3.x + v3.y*v3.y + v3.z*v3.z + v3.w*v3.w;
        }
        for (; r < m; r += 8) {
            float4 v = feats4[rows[r] * DDIM4 + lane];
            acc.x += v.x; acc.y += v.y; acc.z += v.z; acc.w += v.w;
            ff += v.x*v.x + v.y*v.y + v.z*v.z + v.w*v.w;
        }
        __syncthreads();
    }

    comb[wave * DDIM + lane * 4 + 0] = acc.x;
    comb[wave * DDIM + lane * 4 + 1] = acc.y;
    comb[wave * DDIM + lane * 4 + 2] = acc.z;
    comb[wave * DDIM + lane * 4 + 3] = acc.w;
    __syncthreads();

    // threads 0..255 own one dimension each
    float dotv = 0.f, ccv = 0.f;
    if (t < DDIM) {
        float s = 0.f;
#pragma unroll
        for (int w = 0; w < 8; ++w) s += comb[w * DDIM + t];
        float co = centers[c * DDIM + t];
        float nc = (count > 0) ? 0.5f * co + 0.5f * s / (float)count : co;
        dotv = nc * s;                    // count==0 -> s==0 -> 0
        ccv  = nc * nc * (float)count;    // count==0 -> 0
    }

#pragma unroll
    for (int off = 32; off > 0; off >>= 1) {
        ff   += __shfl_down(ff, off);
        dotv += __shfl_down(dotv, off);
        ccv  += __shfl_down(ccv, off);
    }
    if (lane == 0) {
        red[wave * 3 + 0] = ff;
        red[wave * 3 + 1] = dotv;
        red[wave * 3 + 2] = ccv;
    }
    __syncthreads();
    if (t == 0) {
        float a = 0.f, b = 0.f, e = 0.f;
#pragma unroll
        for (int w = 0; w < 8; ++w) {
            a += red[w * 3 + 0];
            b += red[w * 3 + 1];
            e += red[w * 3 + 2];
        }
        atomicAdd(&scalars[0], a);
        atomicAdd(&scalars[1], b);
        atomicAdd(&scalars[2], e);
        __threadfence();
        int old = atomicAdd(ticket, 1);
        if (old == nblocks - 1) {
            __threadfence();
            float A = atomicAdd(&scalars[0], 0.f);
            float Bv = atomicAdd(&scalars[1], 0.f);
            float E = atomicAdd(&scalars[2], 0.f);
            out[0] = 0.5f * invB * (A - 2.f * Bv + E);
        }
    }
}

extern "C" void kernel_launch(void* const* d_in, const int* in_sizes, int n_in,
                              void* d_out, int out_size, void* d_ws, size_t ws_size,
                              hipStream_t stream) {
    const float* feats   = (const float*)d_in[0];
    const float* centers = (const float*)d_in[1];
    const int*   labels  = (const int*)d_in[2];

    int B = in_sizes[2];              // 131072
    int Dv = in_sizes[0] / B;         // 256 (kernel assumes 256)
    int C = in_sizes[1] / Dv;         // 1000
    (void)Dv; (void)n_in; (void)ws_size; (void)out_size;

    int* W = (int*)d_ws;
    int* counts    = W;                        // 1024
    int* offsets   = W + 1024;                 // 1024
    int* cursor    = W + 2048;                 // 1024
    float* scalars = (float*)(W + 3072);       // 16: [0]FF [1]DOT [2]CC
    int* ticket    = W + 3072 + 12;            // scalars slot 12
    int* rowidx    = W + 3072 + 16;            // B

    k0_zero<<<1, 1024, 0, stream>>>(counts, W + 3072);
    k1_hist<<<256, 256, 0, stream>>>(labels, counts, B, C);
    k2_scan<<<1, 1024, 0, stream>>>(counts, offsets, cursor, C);
    int sblocks = (B + 255) / 256;
    if (sblocks > 512) sblocks = 512;
    k3_scatter<<<sblocks, 256, 0, stream>>>(labels, cursor, rowidx, B);
    k4_class<<<C, 512, 0, stream>>>((const float4*)feats, centers, rowidx,
                                    counts, offsets, scalars, ticket,
                                    (float*)d_out, C, 1.0f / (float)B);
}